// Round 8
// baseline (66857.721 us; speedup 1.0000x reference)
//
#include <hip/hip_runtime.h>
#include <math.h>
#include <stdint.h>

// AIS estimator: N=1024 samples, B=128, DIM=DX=64, K=16 anneal steps, 3 leapfrog.
// Round 8: identical to round 7 EXCEPT __launch_bounds__(256) [no min-waves].
// Empirical law from r4-r7: VGPR cap = 256/min_waves_per_EU on this compiler
// ((256,4)->64 regs, (256,3)->84, (256)->252). r7's (256,4) cap of 64 regs
// forced the 16 named float4s + matvec transients into scratch -> 178 GB HBM
// thrash, VALUBusy 2.8%. State needs ~115 regs; uncapping removes the spill.
//  - ALL per-thread state is named float4s, macros only, nothing address-taken.
//  - y-domain reformulation (y = q - mu): kick g = bk*(f - yA) - y with
//    f = c - mu - A.mu precomputed; w = f.y - 0.5 y.A.y + wconst[b].
//  - RNG: JAX partitionable threefry (bits = o0^o1 of (0, idx)), verified r4.
//  - final half-kick skipped: p fully resampled next step. p_noise input dead.

#define WS_A     0
#define WS_MU    4096
#define WS_C     12288
#define WS_XSQ   20480
#define WS_AMU   20608
#define WS_F     28800
#define WS_WC    36992
#define WS_SLW   37120
#define WS_TOTAL (WS_SLW + 131072)

#define LOG2PI 1.8378770664093453f

struct KParams {
  float beta[18];
  float dbeta[17];
  uint32_t fk0[16];
  uint32_t fk1[16];
};

__host__ __device__ static inline void threefry2x32(uint32_t ks0, uint32_t ks1,
                                                    uint32_t x0, uint32_t x1,
                                                    uint32_t& o0, uint32_t& o1) {
  uint32_t ks2 = ks0 ^ ks1 ^ 0x1BD11BDAu;
  x0 += ks0; x1 += ks1;
#define TFR(r) { x0 += x1; x1 = (x1 << (r)) | (x1 >> (32 - (r))); x1 ^= x0; }
  TFR(13) TFR(15) TFR(26) TFR(6)
  x0 += ks1; x1 += ks2 + 1u;
  TFR(17) TFR(29) TFR(16) TFR(24)
  x0 += ks2; x1 += ks0 + 2u;
  TFR(13) TFR(15) TFR(26) TFR(6)
  x0 += ks0; x1 += ks1 + 3u;
  TFR(17) TFR(29) TFR(16) TFR(24)
  x0 += ks1; x1 += ks2 + 4u;
  TFR(13) TFR(15) TFR(26) TFR(6)
  x0 += ks2; x1 += ks0 + 5u;
#undef TFR
  o0 = x0; o1 = x1;
}

__device__ __forceinline__ float u_from_bits(uint32_t bits) {
  const float LO = __uint_as_float(0xBF7FFFFFu);  // nextafter(-1,0) in f32
  float f = __uint_as_float((bits >> 9) | 0x3F800000u) - 1.0f;
  float u = fmaf(f, 2.0f, LO);
  return fmaxf(LO, u);
}

// XLA ErfInv32 (Giles)
__device__ __forceinline__ float erfinv_f(float x) {
  float w = -log1pf(-x * x);
  float p;
  if (w < 5.0f) {
    w -= 2.5f;
    p = 2.81022636e-08f;
    p = fmaf(p, w, 3.43273939e-07f);
    p = fmaf(p, w, -3.5233877e-06f);
    p = fmaf(p, w, -4.39150654e-06f);
    p = fmaf(p, w, 0.00021858087f);
    p = fmaf(p, w, -0.00125372503f);
    p = fmaf(p, w, -0.00417768164f);
    p = fmaf(p, w, 0.246640727f);
    p = fmaf(p, w, 1.50140941f);
  } else {
    w = sqrtf(w) - 3.0f;
    p = -0.000200214257f;
    p = fmaf(p, w, 0.000100950558f);
    p = fmaf(p, w, 0.00134934322f);
    p = fmaf(p, w, -0.00367342844f);
    p = fmaf(p, w, 0.00573950773f);
    p = fmaf(p, w, -0.0076224613f);
    p = fmaf(p, w, 0.00943887047f);
    p = fmaf(p, w, 1.00167406f);
    p = fmaf(p, w, 2.83297682f);
  }
  return p * x;
}

// ---- setup1: A = Wdec Wdec^T ; mu[b][d] ; c[b][d] ; xsq[b]
__global__ void k_setup1(const float* __restrict__ x, const float* __restrict__ Wenc,
                         const float* __restrict__ Wdec, float* __restrict__ ws) {
  int t = blockIdx.x * 256 + threadIdx.x;
  if (t < 4096) {
    int i = t >> 6, j = t & 63;
    float s = 0;
    for (int e = 0; e < 64; ++e) s = fmaf(Wdec[i*64+e], Wdec[j*64+e], s);
    ws[WS_A + t] = s;
  } else if (t < 12288) {
    int u = t - 4096; int b = u >> 6, d = u & 63;
    float s = 0;
    for (int e = 0; e < 64; ++e) s = fmaf(x[b*64+e], Wenc[e*64+d], s);
    ws[WS_MU + u] = s;
  } else if (t < 20480) {
    int u = t - 12288; int b = u >> 6, d = u & 63;
    float s = 0;
    for (int e = 0; e < 64; ++e) s = fmaf(x[b*64+e], Wdec[d*64+e], s);
    ws[WS_C + u] = s;
  } else if (t < 20608) {
    int b = t - 20480;
    float s = 0;
    for (int e = 0; e < 64; ++e) s = fmaf(x[b*64+e], x[b*64+e], s);
    ws[WS_XSQ + b] = s;
  }
}

// ---- setup2: amu[b][d] = (mu A)[d] ; f[b][d] = c - mu - amu
__global__ void k_setup2(float* __restrict__ ws) {
  int t = blockIdx.x * 256 + threadIdx.x;
  if (t < 8192) {
    int b = t >> 6, d = t & 63;
    float s = 0;
    for (int m = 0; m < 64; ++m) s = fmaf(ws[WS_MU + b*64+m], ws[WS_A + m*64+d], s);
    ws[WS_AMU + t] = s;
    ws[WS_F + t] = ws[WS_C + t] - ws[WS_MU + t] - s;
  }
}

// ---- setup3: wconst[b] = -32 log2pi - 0.5 xsq + mu.c - 0.5 |mu|^2 - 0.5 mu.amu
__global__ void k_setup3(float* __restrict__ ws) {
  int b = threadIdx.x;
  if (b < 128) {
    float muc = 0, musq = 0, muamu = 0;
    for (int d = 0; d < 64; ++d) {
      float m = ws[WS_MU + b*64+d];
      muc   = fmaf(m, ws[WS_C + b*64+d], muc);
      musq  = fmaf(m, m, musq);
      muamu = fmaf(m, ws[WS_AMU + b*64+d], muamu);
    }
    ws[WS_WC + b] = -32.0f * LOG2PI - 0.5f * ws[WS_XSQ + b]
                    + muc - 0.5f * musq - 0.5f * muamu;
  }
}

// ---- hot-loop macros: scalar/float4 only, nothing address-taken -----------

#define MV_ACCUM(QS, RP)                                                     \
  {                                                                          \
    float4 a0v = *(const float4*)((RP) + 0);                                 \
    float4 a1v = *(const float4*)((RP) + 4);                                 \
    float4 a2v = *(const float4*)((RP) + 8);                                 \
    float4 a3v = *(const float4*)((RP) + 12);                                \
    acc0.x = fmaf(QS, a0v.x, acc0.x); acc0.y = fmaf(QS, a0v.y, acc0.y);      \
    acc0.z = fmaf(QS, a0v.z, acc0.z); acc0.w = fmaf(QS, a0v.w, acc0.w);      \
    acc1.x = fmaf(QS, a1v.x, acc1.x); acc1.y = fmaf(QS, a1v.y, acc1.y);      \
    acc1.z = fmaf(QS, a1v.z, acc1.z); acc1.w = fmaf(QS, a1v.w, acc1.w);      \
    acc2.x = fmaf(QS, a2v.x, acc2.x); acc2.y = fmaf(QS, a2v.y, acc2.y);      \
    acc2.z = fmaf(QS, a2v.z, acc2.z); acc2.w = fmaf(QS, a2v.w, acc2.w);      \
    acc3.x = fmaf(QS, a3v.x, acc3.x); acc3.y = fmaf(QS, a3v.y, acc3.y);      \
    acc3.z = fmaf(QS, a3v.z, acc3.z); acc3.w = fmaf(QS, a3v.w, acc3.w);      \
  }

#define MATVEC()                                                             \
  acc0 = make_float4(0.f, 0.f, 0.f, 0.f); acc1 = acc0; acc2 = acc0;          \
  acc3 = acc0;                                                               \
  _Pragma("unroll")                                                          \
  for (int m4 = 0; m4 < 16; ++m4) {                                          \
    float4 q4 = *(const float4*)(qme + 4 * m4);                              \
    MV_ACCUM(q4.x, As + (4*m4+0)*64 + d0);                                   \
    MV_ACCUM(q4.y, As + (4*m4+1)*64 + d0);                                   \
    MV_ACCUM(q4.z, As + (4*m4+2)*64 + d0);                                   \
    MV_ACCUM(q4.w, As + (4*m4+3)*64 + d0);                                   \
  }

#define KICK1(PC, FC, AC, YC, DBL)                                           \
  { float g = fmaf(bk, (FC) - (AC), -(YC));                                  \
    PC = fmaf(0.025f, g, PC);                                                \
    if (DBL) PC = fmaf(0.025f, g, PC); }

#define KICK4(PV, FV, AV, YV, DBL)                                           \
  KICK1(PV.x, FV.x, AV.x, YV.x, DBL) KICK1(PV.y, FV.y, AV.y, YV.y, DBL)      \
  KICK1(PV.z, FV.z, AV.z, YV.z, DBL) KICK1(PV.w, FV.w, AV.w, YV.w, DBL)

#define DRIFT4(YV, PV)                                                       \
  YV.x = fmaf(0.05f, PV.x, YV.x); YV.y = fmaf(0.05f, PV.y, YV.y);            \
  YV.z = fmaf(0.05f, PV.z, YV.z); YV.w = fmaf(0.05f, PV.w, YV.w);

#define STORE_Y()                                                            \
  *(float4*)(qme + d0 +  0) = y0; *(float4*)(qme + d0 +  4) = y1;            \
  *(float4*)(qme + d0 +  8) = y2; *(float4*)(qme + d0 + 12) = y3;

#define SUBSTEP(DBL)                                                         \
  MATVEC();                                                                  \
  KICK4(p0, f0, acc0, y0, DBL) KICK4(p1, f1, acc1, y1, DBL)                  \
  KICK4(p2, f2, acc2, y2, DBL) KICK4(p3, f3, acc3, y3, DBL)                  \
  DRIFT4(y0, p0) DRIFT4(y1, p1) DRIFT4(y2, p2) DRIFT4(y3, p3)                \
  STORE_Y();

#define DOT4(S1, S2, FV, YV, AV)                                             \
  S1 = fmaf(FV.x, YV.x, S1); S2 = fmaf(YV.x, AV.x, S2);                      \
  S1 = fmaf(FV.y, YV.y, S1); S2 = fmaf(YV.y, AV.y, S2);                      \
  S1 = fmaf(FV.z, YV.z, S1); S2 = fmaf(YV.z, AV.z, S2);                      \
  S1 = fmaf(FV.w, YV.w, S1); S2 = fmaf(YV.w, AV.w, S2);

#define W_EVAL(WOUT)                                                         \
  {                                                                          \
    MATVEC();                                                                \
    float fy = 0.f, yay = 0.f;                                               \
    DOT4(fy, yay, f0, y0, acc0) DOT4(fy, yay, f1, y1, acc1)                  \
    DOT4(fy, yay, f2, y2, acc2) DOT4(fy, yay, f3, y3, acc3)                  \
    float v = fmaf(-0.5f, yay, fy);                                          \
    v += __shfl_xor(v, 1);                                                   \
    v += __shfl_xor(v, 2);                                                   \
    WOUT = v + wc;                                                           \
  }

#define DRAW(PC, IDX)                                                        \
  { uint32_t o0, o1;                                                         \
    threefry2x32(k0, k1, 0u, base + (IDX), o0, o1);                          \
    PC = 1.41421356f * erfinv_f(u_from_bits(o0 ^ o1)); }

// ---- main: 4 lanes per trajectory (16 dims each), 64 trajectories/block
// __launch_bounds__(256): NO min-waves arg — (256,4) capped VGPR at 64 and
// spilled the working set (r6/r7). LDS 33 KB still gives 3-4 blocks/CU.
__global__ __launch_bounds__(256) void k_main(const float* __restrict__ qn,
                                              const float* __restrict__ ws,
                                              float* __restrict__ slw_out,
                                              KParams P) {
  __shared__ float As[4096];
  __shared__ float qls[64 * 68];  // [traj][dim], pad 68 -> float4-aligned rows
  const int tid = threadIdx.x;
  for (int i = tid; i < 4096; i += 256) As[i] = ws[WS_A + i];
  __syncthreads();

  const int ltraj = tid >> 2, sub = tid & 3;
  const int gtraj = blockIdx.x * 64 + ltraj;
  const int b = gtraj & 127;
  const int d0 = sub * 16;
  float* qme = qls + ltraj * 68;
  const float wc = ws[WS_WC + b];

  float4 f0, f1, f2, f3;
  {
    const float4* fP = (const float4*)(ws + WS_F + b*64 + d0);
    f0 = fP[0]; f1 = fP[1]; f2 = fP[2]; f3 = fP[3];
  }

  float4 y0, y1, y2, y3, p0, p1, p2, p3, acc0, acc1, acc2, acc3;
  float slw = 0.0f;

  // j = 0: y0 = q0 - mu = q_noise (exact)
  {
    const float4* qn4 = (const float4*)(qn + (size_t)gtraj*64 + d0);
    y0 = qn4[0]; y1 = qn4[1]; y2 = qn4[2]; y3 = qn4[3];
    STORE_Y();
  }
  {
    float w0;
    W_EVAL(w0);
    slw = fmaf(P.dbeta[0], w0, slw);
  }

  const uint32_t base = (uint32_t)gtraj * 64u + (uint32_t)d0;
  for (int j = 1; j <= 16; ++j) {
    const float bk = P.beta[j];
    const uint32_t k0 = P.fk0[j-1], k1 = P.fk1[j-1];
    // momentum refresh: partitionable threefry, counter (0, idx), bits = o0^o1
    DRAW(p0.x,  0u) DRAW(p0.y,  1u) DRAW(p0.z,  2u) DRAW(p0.w,  3u)
    DRAW(p1.x,  4u) DRAW(p1.y,  5u) DRAW(p1.z,  6u) DRAW(p1.w,  7u)
    DRAW(p2.x,  8u) DRAW(p2.y,  9u) DRAW(p2.z, 10u) DRAW(p2.w, 11u)
    DRAW(p3.x, 12u) DRAW(p3.y, 13u) DRAW(p3.z, 14u) DRAW(p3.w, 15u)
    // 3 leapfrog: kick(h/2)[first single, then doubled boundary kicks], drift
    SUBSTEP(false)
    SUBSTEP(true)
    SUBSTEP(true)
    float wj;
    W_EVAL(wj);
    slw = fmaf(P.dbeta[j], wj, slw);
  }
  if (sub == 0) slw_out[gtraj] = slw;
}

// ---- logsumexp over n per batch column b
__global__ void k_reduce(const float* __restrict__ slw, float* __restrict__ out) {
  __shared__ float red[256];
  int b = blockIdx.x, t = threadIdx.x;
  float v0 = slw[t*128 + b];
  float v1 = slw[(t+256)*128 + b];
  float v2 = slw[(t+512)*128 + b];
  float v3 = slw[(t+768)*128 + b];
  float m = fmaxf(fmaxf(v0, v1), fmaxf(v2, v3));
  red[t] = m; __syncthreads();
  for (int s = 128; s > 0; s >>= 1) {
    if (t < s) red[t] = fmaxf(red[t], red[t+s]);
    __syncthreads();
  }
  m = red[0]; __syncthreads();
  float sum = expf(v0 - m) + expf(v1 - m) + expf(v2 - m) + expf(v3 - m);
  red[t] = sum; __syncthreads();
  for (int s = 128; s > 0; s >>= 1) {
    if (t < s) red[t] += red[t+s];
    __syncthreads();
  }
  if (t == 0) out[b] = m + logf(red[0]) - 6.93147180559945309f;  // - log(1024)
}

extern "C" void kernel_launch(void* const* d_in, const int* in_sizes, int n_in,
                              void* d_out, int out_size, void* d_ws, size_t ws_size,
                              hipStream_t stream) {
  const float* x    = (const float*)d_in[0];
  const float* Wenc = (const float*)d_in[1];
  const float* Wdec = (const float*)d_in[2];
  const float* qn   = (const float*)d_in[3];
  // d_in[4] (p_noise) is dead: momentum fully resampled every anneal step.
  float* ws  = (float*)d_ws;
  float* out = (float*)d_out;
  if (ws_size < (size_t)WS_TOTAL * sizeof(float)) return;

  KParams P;
  double bb[18];
  for (int i = 0; i < 18; ++i) {
    double tt = (double)i / 17.0;
    bb[i] = 1.0 / (1.0 + exp(-(8.0 * tt - 4.0)));
  }
  for (int i = 0; i < 18; ++i) P.beta[i] = (float)((bb[i] - bb[0]) / (bb[17] - bb[0]));
  for (int j = 0; j <= 16; ++j) P.dbeta[j] = P.beta[j+1] - P.beta[j];
  for (int k = 1; k <= 16; ++k) {
    uint32_t a, c;
    threefry2x32(0u, 42u, 0u, (uint32_t)k, a, c);  // fold_in(key(42), k)
    P.fk0[k-1] = a; P.fk1[k-1] = c;
  }

  hipLaunchKernelGGL(k_setup1, dim3(81), dim3(256), 0, stream, x, Wenc, Wdec, ws);
  hipLaunchKernelGGL(k_setup2, dim3(32), dim3(256), 0, stream, ws);
  hipLaunchKernelGGL(k_setup3, dim3(1), dim3(128), 0, stream, ws);
  hipLaunchKernelGGL(k_main, dim3(2048), dim3(256), 0, stream, qn, ws, ws + WS_SLW, P);
  hipLaunchKernelGGL(k_reduce, dim3(128), dim3(256), 0, stream, ws + WS_SLW, out);
}

// Round 9
// 1521.206 us; speedup vs baseline: 43.9505x; 43.9505x over previous
//
#include <hip/hip_runtime.h>
#include <math.h>
#include <stdint.h>

// AIS estimator: N=1024 samples, B=128, DIM=DX=64, K=16 anneal steps, 3 leapfrog.
// Round 9: synthesis of what worked across r4-r8.
//  - r6's body shape: matvec as a rolled `unroll 4` loop (r7/r8's fully
//    unrolled 4-matvec body caused scheduler live-range explosion -> 130+ GB
//    scratch thrash even with 256 VGPRs).
//  - r7's state repr: named float4s only, nothing address-taken.
//  - budget: state y,p,f,acc = 64 regs + ~40 temps -> __launch_bounds__(256,2)
//    caps at 128 (r4-r8 law: cap = 256/min_waves; 84 spilled, 128 fits).
//  - NEW: acc = A.y carried as loop invariant; w_eval's matvec at end of step
//    j IS kick-1's matvec at step j+1 (y unchanged by refresh) -> 3 matvecs
//    per step, not 4. Bit-identical values.
//  - y-domain (y = q - mu): kick g = bk*(f - yA) - y, f = c - mu - A.mu;
//    w = f.y - 0.5 y.A.y + wconst[b]. Validated r8 (absmax 0.0).
//  - RNG: JAX partitionable threefry (bits = o0^o1 of (0, idx)), verified r4.
//  - final half-kick skipped: p fully resampled next step. p_noise input dead.

#define WS_A     0
#define WS_MU    4096
#define WS_C     12288
#define WS_XSQ   20480
#define WS_AMU   20608
#define WS_F     28800
#define WS_WC    36992
#define WS_SLW   37120
#define WS_TOTAL (WS_SLW + 131072)

#define LOG2PI 1.8378770664093453f

struct KParams {
  float beta[18];
  float dbeta[17];
  uint32_t fk0[16];
  uint32_t fk1[16];
};

__host__ __device__ static inline void threefry2x32(uint32_t ks0, uint32_t ks1,
                                                    uint32_t x0, uint32_t x1,
                                                    uint32_t& o0, uint32_t& o1) {
  uint32_t ks2 = ks0 ^ ks1 ^ 0x1BD11BDAu;
  x0 += ks0; x1 += ks1;
#define TFR(r) { x0 += x1; x1 = (x1 << (r)) | (x1 >> (32 - (r))); x1 ^= x0; }
  TFR(13) TFR(15) TFR(26) TFR(6)
  x0 += ks1; x1 += ks2 + 1u;
  TFR(17) TFR(29) TFR(16) TFR(24)
  x0 += ks2; x1 += ks0 + 2u;
  TFR(13) TFR(15) TFR(26) TFR(6)
  x0 += ks0; x1 += ks1 + 3u;
  TFR(17) TFR(29) TFR(16) TFR(24)
  x0 += ks1; x1 += ks2 + 4u;
  TFR(13) TFR(15) TFR(26) TFR(6)
  x0 += ks2; x1 += ks0 + 5u;
#undef TFR
  o0 = x0; o1 = x1;
}

__device__ __forceinline__ float u_from_bits(uint32_t bits) {
  const float LO = __uint_as_float(0xBF7FFFFFu);  // nextafter(-1,0) in f32
  float f = __uint_as_float((bits >> 9) | 0x3F800000u) - 1.0f;
  float u = fmaf(f, 2.0f, LO);
  return fmaxf(LO, u);
}

// XLA ErfInv32 (Giles)
__device__ __forceinline__ float erfinv_f(float x) {
  float w = -log1pf(-x * x);
  float p;
  if (w < 5.0f) {
    w -= 2.5f;
    p = 2.81022636e-08f;
    p = fmaf(p, w, 3.43273939e-07f);
    p = fmaf(p, w, -3.5233877e-06f);
    p = fmaf(p, w, -4.39150654e-06f);
    p = fmaf(p, w, 0.00021858087f);
    p = fmaf(p, w, -0.00125372503f);
    p = fmaf(p, w, -0.00417768164f);
    p = fmaf(p, w, 0.246640727f);
    p = fmaf(p, w, 1.50140941f);
  } else {
    w = sqrtf(w) - 3.0f;
    p = -0.000200214257f;
    p = fmaf(p, w, 0.000100950558f);
    p = fmaf(p, w, 0.00134934322f);
    p = fmaf(p, w, -0.00367342844f);
    p = fmaf(p, w, 0.00573950773f);
    p = fmaf(p, w, -0.0076224613f);
    p = fmaf(p, w, 0.00943887047f);
    p = fmaf(p, w, 1.00167406f);
    p = fmaf(p, w, 2.83297682f);
  }
  return p * x;
}

// ---- setup1: A = Wdec Wdec^T ; mu[b][d] ; c[b][d] ; xsq[b]
__global__ void k_setup1(const float* __restrict__ x, const float* __restrict__ Wenc,
                         const float* __restrict__ Wdec, float* __restrict__ ws) {
  int t = blockIdx.x * 256 + threadIdx.x;
  if (t < 4096) {
    int i = t >> 6, j = t & 63;
    float s = 0;
    for (int e = 0; e < 64; ++e) s = fmaf(Wdec[i*64+e], Wdec[j*64+e], s);
    ws[WS_A + t] = s;
  } else if (t < 12288) {
    int u = t - 4096; int b = u >> 6, d = u & 63;
    float s = 0;
    for (int e = 0; e < 64; ++e) s = fmaf(x[b*64+e], Wenc[e*64+d], s);
    ws[WS_MU + u] = s;
  } else if (t < 20480) {
    int u = t - 12288; int b = u >> 6, d = u & 63;
    float s = 0;
    for (int e = 0; e < 64; ++e) s = fmaf(x[b*64+e], Wdec[d*64+e], s);
    ws[WS_C + u] = s;
  } else if (t < 20608) {
    int b = t - 20480;
    float s = 0;
    for (int e = 0; e < 64; ++e) s = fmaf(x[b*64+e], x[b*64+e], s);
    ws[WS_XSQ + b] = s;
  }
}

// ---- setup2: amu[b][d] = (mu A)[d] ; f[b][d] = c - mu - amu
__global__ void k_setup2(float* __restrict__ ws) {
  int t = blockIdx.x * 256 + threadIdx.x;
  if (t < 8192) {
    int b = t >> 6, d = t & 63;
    float s = 0;
    for (int m = 0; m < 64; ++m) s = fmaf(ws[WS_MU + b*64+m], ws[WS_A + m*64+d], s);
    ws[WS_AMU + t] = s;
    ws[WS_F + t] = ws[WS_C + t] - ws[WS_MU + t] - s;
  }
}

// ---- setup3: wconst[b] = -32 log2pi - 0.5 xsq + mu.c - 0.5 |mu|^2 - 0.5 mu.amu
__global__ void k_setup3(float* __restrict__ ws) {
  int b = threadIdx.x;
  if (b < 128) {
    float muc = 0, musq = 0, muamu = 0;
    for (int d = 0; d < 64; ++d) {
      float m = ws[WS_MU + b*64+d];
      muc   = fmaf(m, ws[WS_C + b*64+d], muc);
      musq  = fmaf(m, m, musq);
      muamu = fmaf(m, ws[WS_AMU + b*64+d], muamu);
    }
    ws[WS_WC + b] = -32.0f * LOG2PI - 0.5f * ws[WS_XSQ + b]
                    + muc - 0.5f * musq - 0.5f * muamu;
  }
}

// ---- hot-loop macros: scalar/float4 only, nothing address-taken -----------

#define MVROW(QS, RP)                                                        \
  {                                                                          \
    float4 a0v = *(const float4*)((RP) + 0);                                 \
    float4 a1v = *(const float4*)((RP) + 4);                                 \
    float4 a2v = *(const float4*)((RP) + 8);                                 \
    float4 a3v = *(const float4*)((RP) + 12);                                \
    acc0.x = fmaf(QS, a0v.x, acc0.x); acc0.y = fmaf(QS, a0v.y, acc0.y);      \
    acc0.z = fmaf(QS, a0v.z, acc0.z); acc0.w = fmaf(QS, a0v.w, acc0.w);      \
    acc1.x = fmaf(QS, a1v.x, acc1.x); acc1.y = fmaf(QS, a1v.y, acc1.y);      \
    acc1.z = fmaf(QS, a1v.z, acc1.z); acc1.w = fmaf(QS, a1v.w, acc1.w);      \
    acc2.x = fmaf(QS, a2v.x, acc2.x); acc2.y = fmaf(QS, a2v.y, acc2.y);      \
    acc2.z = fmaf(QS, a2v.z, acc2.z); acc2.w = fmaf(QS, a2v.w, acc2.w);      \
    acc3.x = fmaf(QS, a3v.x, acc3.x); acc3.y = fmaf(QS, a3v.y, acc3.y);      \
    acc3.z = fmaf(QS, a3v.z, acc3.z); acc3.w = fmaf(QS, a3v.w, acc3.w);      \
  }

// acc = (y A)[d0..d0+16): rolled loop, modest unroll (r6 shape — the only
// shape that has not triggered scheduler spill-explosion on this compiler)
#define MATVEC()                                                             \
  acc0 = make_float4(0.f, 0.f, 0.f, 0.f); acc1 = acc0; acc2 = acc0;          \
  acc3 = acc0;                                                               \
  _Pragma("unroll 4")                                                        \
  for (int m4 = 0; m4 < 16; ++m4) {                                          \
    float4 q4 = *(const float4*)(qme + 4 * m4);                              \
    const float* rp = As + m4 * 256 + d0;                                    \
    MVROW(q4.x, rp)                                                          \
    MVROW(q4.y, rp + 64)                                                     \
    MVROW(q4.z, rp + 128)                                                    \
    MVROW(q4.w, rp + 192)                                                    \
  }

#define KICK1(PC, FC, AC, YC, DBL)                                           \
  { float g = fmaf(bk, (FC) - (AC), -(YC));                                  \
    PC = fmaf(0.025f, g, PC);                                                \
    if (DBL) PC = fmaf(0.025f, g, PC); }

#define KICK4(PV, FV, AV, YV, DBL)                                           \
  KICK1(PV.x, FV.x, AV.x, YV.x, DBL) KICK1(PV.y, FV.y, AV.y, YV.y, DBL)      \
  KICK1(PV.z, FV.z, AV.z, YV.z, DBL) KICK1(PV.w, FV.w, AV.w, YV.w, DBL)

#define KICK(DBL)                                                            \
  KICK4(p0, f0, acc0, y0, DBL) KICK4(p1, f1, acc1, y1, DBL)                  \
  KICK4(p2, f2, acc2, y2, DBL) KICK4(p3, f3, acc3, y3, DBL)

#define DRIFT4(YV, PV)                                                       \
  YV.x = fmaf(0.05f, PV.x, YV.x); YV.y = fmaf(0.05f, PV.y, YV.y);            \
  YV.z = fmaf(0.05f, PV.z, YV.z); YV.w = fmaf(0.05f, PV.w, YV.w);

#define DRIFT_STORE()                                                        \
  DRIFT4(y0, p0) DRIFT4(y1, p1) DRIFT4(y2, p2) DRIFT4(y3, p3)                \
  *(float4*)(qme + d0 +  0) = y0; *(float4*)(qme + d0 +  4) = y1;            \
  *(float4*)(qme + d0 +  8) = y2; *(float4*)(qme + d0 + 12) = y3;

#define DOT4(S1, S2, FV, YV, AV)                                             \
  S1 = fmaf(FV.x, YV.x, S1); S2 = fmaf(YV.x, AV.x, S2);                      \
  S1 = fmaf(FV.y, YV.y, S1); S2 = fmaf(YV.y, AV.y, S2);                      \
  S1 = fmaf(FV.z, YV.z, S1); S2 = fmaf(YV.z, AV.z, S2);                      \
  S1 = fmaf(FV.w, YV.w, S1); S2 = fmaf(YV.w, AV.w, S2);

// dots only — consumes the invariant acc = y A (no matvec of its own)
#define W_DOTS(WOUT)                                                         \
  {                                                                          \
    float fy = 0.f, yay = 0.f;                                               \
    DOT4(fy, yay, f0, y0, acc0) DOT4(fy, yay, f1, y1, acc1)                  \
    DOT4(fy, yay, f2, y2, acc2) DOT4(fy, yay, f3, y3, acc3)                  \
    float v = fmaf(-0.5f, yay, fy);                                          \
    v += __shfl_xor(v, 1);                                                   \
    v += __shfl_xor(v, 2);                                                   \
    WOUT = v + wc;                                                           \
  }

#define DRAW(PC, IDX)                                                        \
  { uint32_t o0, o1;                                                         \
    threefry2x32(k0, k1, 0u, base + (IDX), o0, o1);                          \
    PC = 1.41421356f * erfinv_f(u_from_bits(o0 ^ o1)); }

// ---- main: 4 lanes per trajectory (16 dims each), 64 trajectories/block
// (256,2): VGPR cap 128. State = y,p,f,acc = 64 regs + ~40 temps fits;
// (256,4)'s cap 64 spilled (r6/r7), uncapped ballooned to 256 + thrash (r8).
__global__ __launch_bounds__(256, 2) void k_main(const float* __restrict__ qn,
                                                 const float* __restrict__ ws,
                                                 float* __restrict__ slw_out,
                                                 KParams P) {
  __shared__ float As[4096];
  __shared__ float qls[64 * 68];  // [traj][dim], pad 68 -> float4 rows, 2-way bank
  const int tid = threadIdx.x;
  for (int i = tid; i < 4096; i += 256) As[i] = ws[WS_A + i];
  __syncthreads();

  const int ltraj = tid >> 2, sub = tid & 3;
  const int gtraj = blockIdx.x * 64 + ltraj;
  const int b = gtraj & 127;
  const int d0 = sub * 16;
  float* qme = qls + ltraj * 68;
  const float wc = ws[WS_WC + b];

  float4 f0, f1, f2, f3;
  {
    const float4* fP = (const float4*)(ws + WS_F + b*64 + d0);
    f0 = fP[0]; f1 = fP[1]; f2 = fP[2]; f3 = fP[3];
  }

  float4 y0, y1, y2, y3, p0, p1, p2, p3, acc0, acc1, acc2, acc3;
  float slw = 0.0f;

  // j = 0: y = q0 - mu = q_noise (exact); establish invariant acc = y A
  {
    const float4* qn4 = (const float4*)(qn + (size_t)gtraj*64 + d0);
    y0 = qn4[0]; y1 = qn4[1]; y2 = qn4[2]; y3 = qn4[3];
    *(float4*)(qme + d0 +  0) = y0; *(float4*)(qme + d0 +  4) = y1;
    *(float4*)(qme + d0 +  8) = y2; *(float4*)(qme + d0 + 12) = y3;
  }
  MATVEC();
  {
    float w0;
    W_DOTS(w0);
    slw = fmaf(P.dbeta[0], w0, slw);
  }

  const uint32_t base = (uint32_t)gtraj * 64u + (uint32_t)d0;
  for (int j = 1; j <= 16; ++j) {
    const float bk = P.beta[j];
    const uint32_t k0 = P.fk0[j-1], k1 = P.fk1[j-1];
    // momentum refresh: partitionable threefry, counter (0, idx), bits = o0^o1
    DRAW(p0.x,  0u) DRAW(p0.y,  1u) DRAW(p0.z,  2u) DRAW(p0.w,  3u)
    DRAW(p1.x,  4u) DRAW(p1.y,  5u) DRAW(p1.z,  6u) DRAW(p1.w,  7u)
    DRAW(p2.x,  8u) DRAW(p2.y,  9u) DRAW(p2.z, 10u) DRAW(p2.w, 11u)
    DRAW(p3.x, 12u) DRAW(p3.y, 13u) DRAW(p3.z, 14u) DRAW(p3.w, 15u)
    // leapfrog x3 with invariant acc = y A at entry (from prev W_DOTS / j=0)
    KICK(false)  // single half-kick, reuses acc
    DRIFT_STORE()
    MATVEC();
    KICK(true)   // doubled boundary half-kicks
    DRIFT_STORE()
    MATVEC();
    KICK(true)
    DRIFT_STORE()
    MATVEC();    // also serves next j's kick1
    float wj;
    W_DOTS(wj);
    slw = fmaf(P.dbeta[j], wj, slw);
  }
  if (sub == 0) slw_out[gtraj] = slw;
}

// ---- logsumexp over n per batch column b
__global__ void k_reduce(const float* __restrict__ slw, float* __restrict__ out) {
  __shared__ float red[256];
  int b = blockIdx.x, t = threadIdx.x;
  float v0 = slw[t*128 + b];
  float v1 = slw[(t+256)*128 + b];
  float v2 = slw[(t+512)*128 + b];
  float v3 = slw[(t+768)*128 + b];
  float m = fmaxf(fmaxf(v0, v1), fmaxf(v2, v3));
  red[t] = m; __syncthreads();
  for (int s = 128; s > 0; s >>= 1) {
    if (t < s) red[t] = fmaxf(red[t], red[t+s]);
    __syncthreads();
  }
  m = red[0]; __syncthreads();
  float sum = expf(v0 - m) + expf(v1 - m) + expf(v2 - m) + expf(v3 - m);
  red[t] = sum; __syncthreads();
  for (int s = 128; s > 0; s >>= 1) {
    if (t < s) red[t] += red[t+s];
    __syncthreads();
  }
  if (t == 0) out[b] = m + logf(red[0]) - 6.93147180559945309f;  // - log(1024)
}

extern "C" void kernel_launch(void* const* d_in, const int* in_sizes, int n_in,
                              void* d_out, int out_size, void* d_ws, size_t ws_size,
                              hipStream_t stream) {
  const float* x    = (const float*)d_in[0];
  const float* Wenc = (const float*)d_in[1];
  const float* Wdec = (const float*)d_in[2];
  const float* qn   = (const float*)d_in[3];
  // d_in[4] (p_noise) is dead: momentum fully resampled every anneal step.
  float* ws  = (float*)d_ws;
  float* out = (float*)d_out;
  if (ws_size < (size_t)WS_TOTAL * sizeof(float)) return;

  KParams P;
  double bb[18];
  for (int i = 0; i < 18; ++i) {
    double tt = (double)i / 17.0;
    bb[i] = 1.0 / (1.0 + exp(-(8.0 * tt - 4.0)));
  }
  for (int i = 0; i < 18; ++i) P.beta[i] = (float)((bb[i] - bb[0]) / (bb[17] - bb[0]));
  for (int j = 0; j <= 16; ++j) P.dbeta[j] = P.beta[j+1] - P.beta[j];
  for (int k = 1; k <= 16; ++k) {
    uint32_t a, c;
    threefry2x32(0u, 42u, 0u, (uint32_t)k, a, c);  // fold_in(key(42), k)
    P.fk0[k-1] = a; P.fk1[k-1] = c;
  }

  hipLaunchKernelGGL(k_setup1, dim3(81), dim3(256), 0, stream, x, Wenc, Wdec, ws);
  hipLaunchKernelGGL(k_setup2, dim3(32), dim3(256), 0, stream, ws);
  hipLaunchKernelGGL(k_setup3, dim3(1), dim3(128), 0, stream, ws);
  hipLaunchKernelGGL(k_main, dim3(2048), dim3(256), 0, stream, qn, ws, ws + WS_SLW, P);
  hipLaunchKernelGGL(k_reduce, dim3(128), dim3(256), 0, stream, ws + WS_SLW, out);
}